// Round 12
// baseline (6092.829 us; speedup 1.0000x reference)
//
#include <hip/hip_runtime.h>
#include <cstdint>

// Reference semantics (validated, absmax=0.0 — DO NOT change arithmetic):
//  - selection on RAW f32 coords, distance = fma(dz,dz, fma(dx,dx, dy*dy))
//    with dx/dy/dz plain f32 subs;
//  - min/argmax exact, FIRST-index tie-break (min global point index);
//  - output coords bf16-RNE-rounded, batch = float b.
//
// R23: R22 proved budget tracks block size (512thr->88, 1024thr->52) but
// 2 waves/SIMD stalls on chains -> net loss. R19's 52 = pz16+m16+temps ->
// R19 was already resident; its cost is INSTRUCTION COUNT at 4 waves/SIMD.
// So: R19 base, minus ~61 VALU/thread/iter:
//  1) fused running scan (m=min(m,d); if(m>bv){bv=m;bs=i}) replaces
//     MAXTREE+IDXCHAIN: 48 vs 93 instr. Exact R8-R11 idiom (ascending,
//     strict >, first-index) — validated absmax 0.0 four times.
//  2) x,y delta via float2 sub -> v_pk_add_f32(neg): one instr for dx,dy;
//     each half an independent IEEE f32 sub == scalar bits; fma tree
//     unchanged.
// Everything else byte-for-byte R19 (5417us): x,y in LDS float2 (128KB),
// z,m in 32 named regs, DPP wave argmax, u64-key block finalize, parity
// double-buffer, one barrier/iter, center = LDS xy + global z.
#pragma clang fp contract(off)

#define B_ 16
#define N_ 16384
#define K_ 4096
#define THREADS_ 1024
#define NW_ (THREADS_ / 64)    // 16 waves per block

#define PTS_LIST(X) \
  X(0) X(1) X(2) X(3) X(4) X(5) X(6) X(7) \
  X(8) X(9) X(10) X(11) X(12) X(13) X(14) X(15)

typedef float f2 __attribute__((ext_vector_type(2)));

// f32 -> bf16 RNE, returned as the bf16-representable f32 (finite inputs)
__device__ __forceinline__ float bfr(float f) {
  union { float f; uint32_t i; } c; c.f = f;
  c.i = (c.i + 0x7FFFu + ((c.i >> 16) & 1u)) & 0xFFFF0000u;
  return c.f;
}

// ---- DPP helpers (ctrl is a template constant) -----------------------------
template <int CTRL>
__device__ __forceinline__ float dpp_fmax(float v) {
  union { float f; int i; } s, p;
  s.f = v;
  p.i = __builtin_amdgcn_update_dpp(0, s.i, CTRL, 0xF, 0xF, false);
  return fmaxf(v, p.f);
}
template <int CTRL>
__device__ __forceinline__ unsigned dpp_umin(unsigned v) {
  const int p = __builtin_amdgcn_update_dpp((int)0xFFFFFFFFu, (int)v,
                                            CTRL, 0xF, 0xF, false);
  const unsigned pu = (unsigned)p;
  return pu < v ? pu : v;
}

// wave-wide (max bv, min bg among maxed) -> (wv, wg), uniform in all lanes.
__device__ __forceinline__ void wave_argmax(float bv, unsigned bg,
                                            float& wv, unsigned& wg) {
  float v = bv;
  v = dpp_fmax<0x111>(v);  // row_shr:1
  v = dpp_fmax<0x112>(v);  // row_shr:2
  v = dpp_fmax<0x114>(v);  // row_shr:4
  v = dpp_fmax<0x118>(v);  // row_shr:8
  v = dpp_fmax<0x142>(v);  // row_bcast:15
  v = dpp_fmax<0x143>(v);  // row_bcast:31
  union { float f; int i; } mx;
  mx.i = __builtin_amdgcn_readlane(__builtin_bit_cast(int, v), 63);
  unsigned c = (bv == mx.f) ? bg : 0xFFFFFFFFu;
  c = dpp_umin<0x111>(c);
  c = dpp_umin<0x112>(c);
  c = dpp_umin<0x114>(c);
  c = dpp_umin<0x118>(c);
  c = dpp_umin<0x142>(c);
  c = dpp_umin<0x143>(c);
  wg = (unsigned)__builtin_amdgcn_readlane((int)c, 63);
  wv = mx.f;
}

// u64 key max over a DPP lane-permutation (block-finalize butterfly; key is
// (f32bits(dist)<<32)|~idx so u64 max == (max dist, min index)). Exact.
template <int CTRL>
__device__ __forceinline__ unsigned long long kmax_dpp(unsigned long long k) {
  const int lo = (int)(unsigned)k;
  const int hi = (int)(unsigned)(k >> 32);
  const int plo = __builtin_amdgcn_update_dpp(lo, lo, CTRL, 0xF, 0xF, true);
  const int phi = __builtin_amdgcn_update_dpp(hi, hi, CTRL, 0xF, 0xF, true);
  const unsigned long long ok =
      ((unsigned long long)(unsigned)phi << 32) | (unsigned)plo;
  return ok > k ? ok : k;
}

__global__ __attribute__((amdgpu_flat_work_group_size(THREADS_, THREADS_),
                          amdgpu_waves_per_eu(4, 4)))
void fps_kernel(const float* __restrict__ x, float* __restrict__ out)
{
#pragma clang fp contract(off)
  const int b    = blockIdx.x;
  const int t    = threadIdx.x;
  const int lane = t & 63;
  const int wave = t >> 6;

  // x,y of all 16384 points (128 KB). Thread t reads only slots {i*1024+t}
  // in the update loop; center reads are uniform-address broadcasts.
  __shared__ f2 s_xy[N_];
  // parity-double-buffered per-wave argmax keys: one barrier per iteration
  __shared__ unsigned long long s_key[2][NW_];

  const float* xb  = x + (size_t)b * (N_ * 3);
  float* out_x     = out;                        // [B*K*3] f32 (bf16-grid values)
  float* out_batch = out + (size_t)B_ * K_ * 3;  // [B*K]   f32 cloud ids

  // batch output (buffer re-poisoned every call -> rewrite every call)
  {
    const float bb = (float)b;
    for (int i = t; i < K_; i += THREADS_) out_batch[b * K_ + i] = bb;
  }

  // z and running-min in named registers; x,y staged to LDS
#define DECLP(i) float pz##i, m##i;
  PTS_LIST(DECLP)
#undef DECLP

#define LOADP(i) { const float* p_ = xb + 3 * ((i) * THREADS_ + t); \
                   f2 v_; v_.x = p_[0]; v_.y = p_[1];               \
                   s_xy[(i) * THREADS_ + t] = v_;                   \
                   pz##i = p_[2]; m##i = __builtin_inff(); }
  PTS_LIST(LOADP)
#undef LOADP

  // dist update (bit-exact FMA-V1) + fused running argmax scan.
  // f2 subtraction -> v_pk_add_f32(neg): each half an IEEE f32 sub ==
  // scalar bits. Ascending slot scan, strict > keeps FIRST max (R8-R11).
#define UPD(i) { const f2 v_ = s_xy[(i) * THREADS_ + t];                        \
                 const f2 d2_ = v_ - c2;                                        \
                 const float dz_ = pz##i - cz;                                  \
                 const float d_  = __builtin_fmaf(dz_, dz_,                     \
                                   __builtin_fmaf(d2_.x, d2_.x,                 \
                                                  d2_.y * d2_.y));              \
                 m##i = fminf(m##i, d_);                                        \
                 if (m##i > bv) { bv = m##i; bs = (i); } }

  // per-thread (bv,bs) -> wave argmax -> per-wave key in LDS
#define REDUCE_AND_POST(PARITY) {                                        \
      const unsigned bg = (unsigned)(bs * THREADS_ + t);                 \
      float wv; unsigned wg;                                             \
      wave_argmax(bv, bg, wv, wg);                                       \
      if (lane == 0) {                                                   \
        union { float f; unsigned u; } cv; cv.f = wv;                    \
        s_key[PARITY][wave] =                                            \
            ((unsigned long long)cv.u << 32) | (unsigned)~wg;            \
      } }

  // ---- iteration 0: seed = point 0 ----
  float cx = xb[0], cy = xb[1], cz = xb[2];
  if (t == 0) {
    const uint64_t o = ((uint64_t)b * K_) * 3;
    out_x[o + 0] = bfr(cx); out_x[o + 1] = bfr(cy); out_x[o + 2] = bfr(cz);
  }

  {
    f2 c2; c2.x = cx; c2.y = cy;
    float bv = -1.0f; int bs = 0;
    PTS_LIST(UPD)                    // m_i = d_i (min with +inf)
    REDUCE_AND_POST(0)
  }
  __syncthreads();

  // ---- iterations 1..K-1 ----
  for (int j = 1; j < K_; ++j) {
    const int rp = (j - 1) & 1;
    const int wp = j & 1;

    // finalize block argmax: 16 per-wave keys broadcast (lane&15), 4 DPP
    // levels within each 16-lane row -> every lane holds the block winner.
    unsigned long long k = s_key[rp][lane & 15];
    k = kmax_dpp<0xB1>(k);    // quad_perm lane^1
    k = kmax_dpp<0x4E>(k);    // quad_perm lane^2
    k = kmax_dpp<0x141>(k);   // row_half_mirror (lane^7, covers ^4)
    k = kmax_dpp<0x140>(k);   // row_mirror (lane^15, covers ^8)
    const unsigned idx = ~(unsigned)k;           // winner global point index
    const int gu = __builtin_amdgcn_readfirstlane((int)idx);

    // center: x,y from LDS (uniform broadcast read), z from global (L2;
    // latency hides under the cz-independent xy VALU below)
    const f2 cxy = s_xy[gu];
    cx = cxy.x; cy = cxy.y;
    cz = xb[3 * gu + 2];
    if (t == 0) {
      const uint64_t o = ((uint64_t)b * K_ + j) * 3;
      out_x[o + 0] = bfr(cx); out_x[o + 1] = bfr(cy); out_x[o + 2] = bfr(cz);
    }

    // update mind + fused scan + wave reduce for next round
    {
      f2 c2; c2.x = cx; c2.y = cy;
      float bv = -1.0f; int bs = 0;
      PTS_LIST(UPD)
      REDUCE_AND_POST(wp)
    }
    __syncthreads();
  }
#undef UPD
#undef REDUCE_AND_POST

}

extern "C" void kernel_launch(void* const* d_in, const int* in_sizes, int n_in,
                              void* d_out, int out_size, void* d_ws, size_t ws_size,
                              hipStream_t stream) {
  const float* x = (const float*)d_in[0];  // f32, [B*N, 3]
  float* out     = (float*)d_out;          // f32: [B*K*3] coords + [B*K] batch
  (void)in_sizes; (void)n_in; (void)out_size; (void)d_ws; (void)ws_size;
  hipLaunchKernelGGL(fps_kernel, dim3(B_), dim3(THREADS_), 0, stream, x, out);
}